// Round 1
// baseline (671.342 us; speedup 1.0000x reference)
//
#include <hip/hip_runtime.h>

// SlotAttention MI355X implementation.
// Pipeline: k0 (transpose Wk|Wv -> bf16), k1 (LN(inputs) -> k[b][n][c], vT[b][c][n] bf16, MFMA),
// kq (q from initial slots), then 3x { k2 (fused dots/softmax/renorm-accumulate partials, MFMA),
// k3 (reduce partials -> updates -> GRU -> MLP -> new slots (+ q for next iter)) }.
// Workspace layout (needs ~260.5MB):
//   kmat  bf16 [32][16384][128]   @ 0          (134217728 B)
//   vT    bf16 [32][128][16384]   @ 134217728  (134217728 B)
//   qbuf  bf16 [32][16][128]      @ 268435456  (131072 B)
//   wkvT  bf16 [256][128]         @ 268566528  (65536 B)
//   nump  f32  [32][16][16][128]  @ 268632064  (4194304 B)
//   denp  f32  [32][16][16]       @ 272826368  (32768 B)
//   sbuf  f32  [32][16][128]      @ 272859136  (262144 B)

#define NTOT 16384
#define CDIM 128

using short8 = __attribute__((ext_vector_type(8))) short;
using f32x4  = __attribute__((ext_vector_type(4))) float;

__device__ __forceinline__ unsigned short f2bf(float x) {
  union { float f; unsigned u; } v; v.f = x;
  unsigned r = v.u + 0x7FFFu + ((v.u >> 16) & 1u);
  return (unsigned short)(r >> 16);
}
__device__ __forceinline__ float sigf(float x) { return 1.f / (1.f + __expf(-x)); }
__device__ __forceinline__ float tanhfast(float x) {
  x = fminf(fmaxf(x, -15.f), 15.f);
  float e = __expf(2.f * x);
  return (e - 1.f) / (e + 1.f);
}

// ---- K0: build WkvT[j][c] = (j<128 ? Wk[c][j] : Wv[c][j-128]) as bf16 ----
__global__ void k0_prep(const float* __restrict__ Wk, const float* __restrict__ Wv,
                        unsigned short* __restrict__ wkvT) {
  int idx = blockIdx.x * 256 + threadIdx.x;   // 0..32767
  int j = idx >> 7, c = idx & 127;
  float val = (j < 128) ? Wk[c * 128 + j] : Wv[c * 128 + (j - 128)];
  wkvT[j * 128 + c] = f2bf(val);
}

// ---- K1: LN(inputs) -> xln (bf16, LDS) -> MFMA with Wk/Wv -> k, vT ----
__global__ __launch_bounds__(256) void k1_lnkv(
    const float* __restrict__ in, const float* __restrict__ gam,
    const float* __restrict__ bet, const unsigned short* __restrict__ wkvT,
    unsigned short* __restrict__ kmat, unsigned short* __restrict__ vT) {
  __shared__ __align__(16) unsigned short xln[64 * 128];    // 16KB, xor-swizzled
  __shared__ __align__(16) unsigned short wlds[128 * 128];  // 32KB, xor-swizzled
  const int t = threadIdx.x;
  const long rowbase = (long)blockIdx.x * 64;

  // stage k-weight half (wkvT rows 0..127)
  #pragma unroll
  for (int i = 0; i < 8; ++i) {
    int chunk = t + i * 256;  // 16B chunk id
    int row = chunk >> 4;
    unsigned ba = ((unsigned)chunk * 16u) ^ (((unsigned)row & 7u) << 4);
    *(short8*)((char*)wlds + ba) = *(const short8*)(wkvT + chunk * 8);
  }

  // LayerNorm of 64 input rows (4 threads/row, 32 elems each)
  {
    const int row = t >> 2, seg = t & 3;
    const float* src = in + (rowbase + row) * CDIM + seg * 32;
    float x[32];
    float s1 = 0.f, s2 = 0.f;
    #pragma unroll
    for (int i = 0; i < 8; ++i) {
      float4 v4 = ((const float4*)src)[i];
      x[i*4+0] = v4.x; x[i*4+1] = v4.y; x[i*4+2] = v4.z; x[i*4+3] = v4.w;
    }
    #pragma unroll
    for (int i = 0; i < 32; ++i) { s1 += x[i]; s2 += x[i] * x[i]; }
    s1 += __shfl_xor(s1, 1); s1 += __shfl_xor(s1, 2);
    s2 += __shfl_xor(s2, 1); s2 += __shfl_xor(s2, 2);
    float mean = s1 * (1.f / 128.f);
    float var  = s2 * (1.f / 128.f) - mean * mean;
    float rstd = rsqrtf(var + 1e-5f);
    #pragma unroll
    for (int i = 0; i < 16; ++i) {
      int c = seg * 32 + i * 2;
      float y0 = (x[i*2+0] - mean) * rstd * gam[c]   + bet[c];
      float y1 = (x[i*2+1] - mean) * rstd * gam[c+1] + bet[c+1];
      unsigned pk = (unsigned)f2bf(y0) | ((unsigned)f2bf(y1) << 16);
      unsigned ba = ((unsigned)(row * 256 + c * 2)) ^ (((unsigned)row & 7u) << 4);
      *(unsigned*)((char*)xln + ba) = pk;
    }
  }
  __syncthreads();

  const int w = t >> 6, l = t & 63, lr = l & 15, lg = l >> 4;
  short8 af[4];
  #pragma unroll
  for (int kb = 0; kb < 4; ++kb) {
    int row = w * 16 + lr;
    unsigned ba = ((unsigned)(row * 256 + (kb * 32 + lg * 8) * 2)) ^ (((unsigned)row & 7u) << 4);
    af[kb] = *(const short8*)((const char*)xln + ba);
  }

  // pass 0: k output (cols 0..127), k[b][n][c] row-major
  #pragma unroll
  for (int tile = 0; tile < 8; ++tile) {
    f32x4 acc = {0.f, 0.f, 0.f, 0.f};
    #pragma unroll
    for (int kb = 0; kb < 4; ++kb) {
      int rw2 = tile * 16 + lr;
      unsigned ba = ((unsigned)(rw2 * 256 + (kb * 32 + lg * 8) * 2)) ^ (((unsigned)rw2 & 7u) << 4);
      short8 bf = *(const short8*)((const char*)wlds + ba);
      acc = __builtin_amdgcn_mfma_f32_16x16x32_bf16(af[kb], bf, acc, 0, 0, 0);
    }
    #pragma unroll
    for (int r = 0; r < 4; ++r) {
      long rw = rowbase + w * 16 + lg * 4 + r;
      kmat[rw * CDIM + tile * 16 + lr] = f2bf(acc[r]);
    }
  }
  __syncthreads();
  // stage v-weight half (wkvT rows 128..255)
  #pragma unroll
  for (int i = 0; i < 8; ++i) {
    int chunk = t + i * 256;
    int row = chunk >> 4;
    unsigned ba = ((unsigned)chunk * 16u) ^ (((unsigned)row & 7u) << 4);
    *(short8*)((char*)wlds + ba) = *(const short8*)(wkvT + 16384 + chunk * 8);
  }
  __syncthreads();
  // pass 1: v output, stored transposed vT[b][c][n] (4 consecutive n per lane -> 8B store)
  #pragma unroll
  for (int tile = 0; tile < 8; ++tile) {
    f32x4 acc = {0.f, 0.f, 0.f, 0.f};
    #pragma unroll
    for (int kb = 0; kb < 4; ++kb) {
      int rw2 = tile * 16 + lr;
      unsigned ba = ((unsigned)(rw2 * 256 + (kb * 32 + lg * 8) * 2)) ^ (((unsigned)rw2 & 7u) << 4);
      short8 bf = *(const short8*)((const char*)wlds + ba);
      acc = __builtin_amdgcn_mfma_f32_16x16x32_bf16(af[kb], bf, acc, 0, 0, 0);
    }
    int c = tile * 16 + lr;
    long rw = rowbase + w * 16 + lg * 4;
    long bb = rw >> 14;
    long n  = rw & 16383;
    ushort4 u = {f2bf(acc[0]), f2bf(acc[1]), f2bf(acc[2]), f2bf(acc[3])};
    *(ushort4*)(vT + bb * (128L * NTOT) + (long)c * NTOT + n) = u;
  }
}

// ---- Kq: q = (LN_s(slots) @ Wq) / sqrt(C) -> bf16 (initial iteration) ----
__global__ __launch_bounds__(512) void kq_init(
    const float* __restrict__ slots, const float* __restrict__ lnsg,
    const float* __restrict__ lnsb, const float* __restrict__ Wq,
    unsigned short* __restrict__ qout) {
  const int b = blockIdx.x, t = threadIdx.x;
  const int s = t >> 5, jq = (t & 31) * 4;
  __shared__ __align__(16) float lnq[2048];
  f32x4 x4 = *(const f32x4*)(slots + b * 2048 + t * 4);
  float ps = x4[0] + x4[1] + x4[2] + x4[3];
  float pq = x4[0]*x4[0] + x4[1]*x4[1] + x4[2]*x4[2] + x4[3]*x4[3];
  ps += __shfl_xor(ps, 1); ps += __shfl_xor(ps, 2); ps += __shfl_xor(ps, 4); ps += __shfl_xor(ps, 8); ps += __shfl_xor(ps, 16);
  pq += __shfl_xor(pq, 1); pq += __shfl_xor(pq, 2); pq += __shfl_xor(pq, 4); pq += __shfl_xor(pq, 8); pq += __shfl_xor(pq, 16);
  float mean = ps * (1.f / 128.f);
  float var  = pq * (1.f / 128.f) - mean * mean;
  float rstd = rsqrtf(var + 1e-5f);
  f32x4 l4 = (x4 - mean) * rstd * (*(const f32x4*)(lnsg + jq)) + (*(const f32x4*)(lnsb + jq));
  *(f32x4*)(lnq + t * 4) = l4;
  __syncthreads();
  f32x4 qa = {0.f, 0.f, 0.f, 0.f};
  const float* wqp = Wq + jq;
  const float* qrow = lnq + s * 128;
  for (int c = 0; c < 128; ++c)
    qa += *(const f32x4*)(wqp + c * 128) * qrow[c];
  qa *= 0.08838834764831845f;  // 1/sqrt(128)
  ushort4 uq = {f2bf(qa[0]), f2bf(qa[1]), f2bf(qa[2]), f2bf(qa[3])};
  *(ushort4*)(qout + b * 2048 + t * 4) = uq;
}

// ---- K2: fused dots -> softmax(S) -> (+EPS) -> accumulate num/den over n ----
__global__ __launch_bounds__(256) void k2_attn(
    const unsigned short* __restrict__ kmat, const unsigned short* __restrict__ vT,
    const unsigned short* __restrict__ qm,
    float* __restrict__ nump, float* __restrict__ denp) {
  const int nb = blockIdx.x, b = blockIdx.y;
  const int t = threadIdx.x, w = t >> 6, l = t & 63, lr = l & 15, lg = l >> 4;
  __shared__ __align__(16) unsigned short pbuf[4][512];  // per-wave p tile [16s][32n], swizzled
  __shared__ __align__(16) float redbuf[4][2048];        // per-wave partial num [16s][128c]
  __shared__ float denbuf[4][16];

  const unsigned short* kb_ = kmat + (long)b * (NTOT * CDIM);
  const unsigned short* vb  = vT + (long)b * (CDIM * (long)NTOT);
  const unsigned short* qb  = qm + b * (16 * CDIM);

  short8 qf[4];
  #pragma unroll
  for (int kk = 0; kk < 4; ++kk)
    qf[kk] = *(const short8*)(qb + lr * CDIM + kk * 32 + lg * 8);

  f32x4 acc[8];
  #pragma unroll
  for (int i = 0; i < 8; ++i) acc[i] = (f32x4){0.f, 0.f, 0.f, 0.f};
  float den0 = 0.f, den1 = 0.f, den2 = 0.f, den3 = 0.f;

  char* pw = (char*)&pbuf[w][0];

  for (int it = 0; it < 8; ++it) {
    const int n0 = nb * 1024 + (it * 4 + w) * 32;
    #pragma unroll
    for (int half = 0; half < 2; ++half) {
      f32x4 d = {0.f, 0.f, 0.f, 0.f};
      const unsigned short* krow = kb_ + (n0 + half * 16 + lr) * CDIM + lg * 8;
      #pragma unroll
      for (int kk = 0; kk < 4; ++kk) {
        short8 kf = *(const short8*)(krow + kk * 32);
        d = __builtin_amdgcn_mfma_f32_16x16x32_bf16(qf[kk], kf, d, 0, 0, 0);
      }
      // softmax over s (16 rows of D, spread over 4 regs x 4 lane-groups)
      float e0 = __expf(d[0]), e1 = __expf(d[1]), e2 = __expf(d[2]), e3 = __expf(d[3]);
      float cs = e0 + e1 + e2 + e3;
      cs += __shfl_xor(cs, 16);
      cs += __shfl_xor(cs, 32);
      float inv = 1.f / cs;
      float p0 = e0 * inv + 1e-8f, p1 = e1 * inv + 1e-8f,
            p2 = e2 * inv + 1e-8f, p3 = e3 * inv + 1e-8f;
      den0 += p0; den1 += p1; den2 += p2; den3 += p3;
      unsigned short pv0 = f2bf(p0), pv1 = f2bf(p1), pv2 = f2bf(p2), pv3 = f2bf(p3);
      int nn = half * 16 + lr;
      {
        int s0 = lg * 4;
        unsigned ba0 = ((unsigned)((s0+0) * 64 + nn * 2)) ^ (((unsigned)(s0+0) & 3u) << 4);
        unsigned ba1 = ((unsigned)((s0+1) * 64 + nn * 2)) ^ (((unsigned)(s0+1) & 3u) << 4);
        unsigned ba2 = ((unsigned)((s0+2) * 64 + nn * 2)) ^ (((unsigned)(s0+2) & 3u) << 4);
        unsigned ba3 = ((unsigned)((s0+3) * 64 + nn * 2)) ^ (((unsigned)(s0+3) & 3u) << 4);
        *(unsigned short*)(pw + ba0) = pv0;
        *(unsigned short*)(pw + ba1) = pv1;
        *(unsigned short*)(pw + ba2) = pv2;
        *(unsigned short*)(pw + ba3) = pv3;
      }
    }
    asm volatile("" ::: "memory");  // same-wave LDS RAW: DS ops are in-order; fence the compiler
    short8 pf;
    {
      unsigned ba = ((unsigned)(lr * 64 + lg * 16)) ^ (((unsigned)lr & 3u) << 4);
      pf = *(const short8*)(pw + ba);
    }
    // numT[c][s] += vT-frag * p-frag over K=32 n's
    #pragma unroll
    for (int ct = 0; ct < 8; ++ct) {
      const unsigned short* vrow = vb + (ct * 16 + lr) * NTOT + n0 + lg * 8;
      short8 vf = *(const short8*)vrow;
      acc[ct] = __builtin_amdgcn_mfma_f32_16x16x32_bf16(vf, pf, acc[ct], 0, 0, 0);
    }
    asm volatile("" ::: "memory");
  }

  // per-wave partials -> LDS (store as [s][c] so the global write is coalesced)
  float* rw_ = &redbuf[w][0];
  #pragma unroll
  for (int ct = 0; ct < 8; ++ct)
    *(f32x4*)(rw_ + lr * 128 + ct * 16 + lg * 4) = acc[ct];

  den0 += __shfl_xor(den0, 1); den0 += __shfl_xor(den0, 2); den0 += __shfl_xor(den0, 4); den0 += __shfl_xor(den0, 8);
  den1 += __shfl_xor(den1, 1); den1 += __shfl_xor(den1, 2); den1 += __shfl_xor(den1, 4); den1 += __shfl_xor(den1, 8);
  den2 += __shfl_xor(den2, 1); den2 += __shfl_xor(den2, 2); den2 += __shfl_xor(den2, 4); den2 += __shfl_xor(den2, 8);
  den3 += __shfl_xor(den3, 1); den3 += __shfl_xor(den3, 2); den3 += __shfl_xor(den3, 4); den3 += __shfl_xor(den3, 8);
  if (lr == 0) {
    denbuf[w][lg * 4 + 0] = den0;
    denbuf[w][lg * 4 + 1] = den1;
    denbuf[w][lg * 4 + 2] = den2;
    denbuf[w][lg * 4 + 3] = den3;
  }
  __syncthreads();

  float* outp = nump + ((long)b * 16 + nb) * 2048;
  for (int i = t; i < 512; i += 256) {
    f32x4 v0 = *(const f32x4*)(&redbuf[0][0] + i * 4);
    f32x4 v1 = *(const f32x4*)(&redbuf[1][0] + i * 4);
    f32x4 v2 = *(const f32x4*)(&redbuf[2][0] + i * 4);
    f32x4 v3 = *(const f32x4*)(&redbuf[3][0] + i * 4);
    *(f32x4*)(outp + i * 4) = (v0 + v1) + (v2 + v3);
  }
  if (t < 16)
    denp[(b * 16 + nb) * 16 + t] = denbuf[0][t] + denbuf[1][t] + denbuf[2][t] + denbuf[3][t];
}

// ---- K3: reduce partials -> updates -> GRU -> MLP -> slots_out (+ q next) ----
__global__ __launch_bounds__(512) void k3_update(
    const float* __restrict__ sprev, const float* __restrict__ nump,
    const float* __restrict__ denp, const float* __restrict__ wih,
    const float* __restrict__ whh, const float* __restrict__ bih,
    const float* __restrict__ bhh, const float* __restrict__ w1,
    const float* __restrict__ b1, const float* __restrict__ w2,
    const float* __restrict__ b2, const float* __restrict__ lnfg,
    const float* __restrict__ lnfb, const float* __restrict__ lnsg,
    const float* __restrict__ lnsb, const float* __restrict__ Wq,
    float* __restrict__ sout, unsigned short* __restrict__ qout, const int doq) {
  const int b = blockIdx.x, t = threadIdx.x;
  const int s = t >> 5, jq = (t & 31) * 4;
  __shared__ __align__(16) float sp[2048];
  __shared__ __align__(16) float upd[2048];
  __shared__ __align__(16) float lnb[2048];
  __shared__ float dsh[16];

  f32x4 hp4 = *(const f32x4*)(sprev + b * 2048 + t * 4);
  *(f32x4*)(sp + t * 4) = hp4;
  if (t < 16) {
    float d = 0.f;
    #pragma unroll
    for (int nb = 0; nb < 16; ++nb) d += denp[(b * 16 + nb) * 16 + t];
    dsh[t] = d;
  }
  f32x4 nsum = {0.f, 0.f, 0.f, 0.f};
  for (int nb = 0; nb < 16; ++nb)
    nsum += *(const f32x4*)(nump + ((long)b * 16 + nb) * 2048 + t * 4);
  __syncthreads();
  *(f32x4*)(upd + t * 4) = nsum * (1.f / dsh[s]);
  __syncthreads();

  // GRU: gi = upd@wih + bih ; gh = sp@whh + bhh ; gates r,z,n
  f32x4 ir = {0,0,0,0}, iz = {0,0,0,0}, inn = {0,0,0,0};
  f32x4 hr = {0,0,0,0}, hz = {0,0,0,0}, hn = {0,0,0,0};
  const float* wih_p = wih + jq;
  const float* whh_p = whh + jq;
  const float* ur  = upd + s * 128;
  const float* hrw = sp + s * 128;
  for (int c = 0; c < 128; ++c) {
    float u = ur[c], h = hrw[c];
    ir  += *(const f32x4*)(wih_p + c * 384)       * u;
    iz  += *(const f32x4*)(wih_p + c * 384 + 128) * u;
    inn += *(const f32x4*)(wih_p + c * 384 + 256) * u;
    hr  += *(const f32x4*)(whh_p + c * 384)       * h;
    hz  += *(const f32x4*)(whh_p + c * 384 + 128) * h;
    hn  += *(const f32x4*)(whh_p + c * 384 + 256) * h;
  }
  ir  += *(const f32x4*)(bih + jq);
  iz  += *(const f32x4*)(bih + 128 + jq);
  inn += *(const f32x4*)(bih + 256 + jq);
  hr  += *(const f32x4*)(bhh + jq);
  hz  += *(const f32x4*)(bhh + 128 + jq);
  hn  += *(const f32x4*)(bhh + 256 + jq);
  f32x4 snew;
  #pragma unroll
  for (int i = 0; i < 4; ++i) {
    float r = sigf(ir[i] + hr[i]);
    float z = sigf(iz[i] + hz[i]);
    float n = tanhfast(inn[i] + r * hn[i]);
    snew[i] = (1.f - z) * n + z * hp4[i];
  }

  // ln_ff stats via shfl over the 32 threads of this row
  float ps = snew[0] + snew[1] + snew[2] + snew[3];
  float pq = snew[0]*snew[0] + snew[1]*snew[1] + snew[2]*snew[2] + snew[3]*snew[3];
  ps += __shfl_xor(ps, 1); ps += __shfl_xor(ps, 2); ps += __shfl_xor(ps, 4); ps += __shfl_xor(ps, 8); ps += __shfl_xor(ps, 16);
  pq += __shfl_xor(pq, 1); pq += __shfl_xor(pq, 2); pq += __shfl_xor(pq, 4); pq += __shfl_xor(pq, 8); pq += __shfl_xor(pq, 16);
  float mean = ps * (1.f / 128.f);
  float var  = pq * (1.f / 128.f) - mean * mean;
  float rstd = rsqrtf(var + 1e-5f);
  f32x4 lf = (snew - mean) * rstd * (*(const f32x4*)(lnfg + jq)) + (*(const f32x4*)(lnfb + jq));
  *(f32x4*)(lnb + t * 4) = lf;
  __syncthreads();

  // MLP layer 1 + ReLU
  f32x4 ha = {0,0,0,0};
  const float* w1p = w1 + jq;
  const float* lrow = lnb + s * 128;
  for (int c = 0; c < 128; ++c)
    ha += *(const f32x4*)(w1p + c * 128) * lrow[c];
  ha += *(const f32x4*)(b1 + jq);
  #pragma unroll
  for (int i = 0; i < 4; ++i) ha[i] = fmaxf(ha[i], 0.f);
  *(f32x4*)(upd + t * 4) = ha;   // safe: all GRU reads of upd finished before lnb barrier
  __syncthreads();

  // MLP layer 2 + residual
  f32x4 oa = {0,0,0,0};
  const float* w2p = w2 + jq;
  const float* hrow = upd + s * 128;
  for (int c = 0; c < 128; ++c)
    oa += *(const f32x4*)(w2p + c * 128) * hrow[c];
  oa += *(const f32x4*)(b2 + jq);
  f32x4 sf = snew + oa;
  *(f32x4*)(sout + b * 2048 + t * 4) = sf;

  if (doq) {
    float qs = sf[0] + sf[1] + sf[2] + sf[3];
    float qz = sf[0]*sf[0] + sf[1]*sf[1] + sf[2]*sf[2] + sf[3]*sf[3];
    qs += __shfl_xor(qs, 1); qs += __shfl_xor(qs, 2); qs += __shfl_xor(qs, 4); qs += __shfl_xor(qs, 8); qs += __shfl_xor(qs, 16);
    qz += __shfl_xor(qz, 1); qz += __shfl_xor(qz, 2); qz += __shfl_xor(qz, 4); qz += __shfl_xor(qz, 8); qz += __shfl_xor(qz, 16);
    float m2 = qs * (1.f / 128.f);
    float v2 = qz * (1.f / 128.f) - m2 * m2;
    float rs2 = rsqrtf(v2 + 1e-5f);
    f32x4 lq = (sf - m2) * rs2 * (*(const f32x4*)(lnsg + jq)) + (*(const f32x4*)(lnsb + jq));
    *(f32x4*)(sp + t * 4) = lq;   // reuse sp
    __syncthreads();
    f32x4 qa = {0,0,0,0};
    const float* wqp = Wq + jq;
    const float* qrow = sp + s * 128;
    for (int c = 0; c < 128; ++c)
      qa += *(const f32x4*)(wqp + c * 128) * qrow[c];
    qa *= 0.08838834764831845f;
    ushort4 uq = {f2bf(qa[0]), f2bf(qa[1]), f2bf(qa[2]), f2bf(qa[3])};
    *(ushort4*)(qout + b * 2048 + t * 4) = uq;
  }
}

extern "C" void kernel_launch(void* const* d_in, const int* in_sizes, int n_in,
                              void* d_out, int out_size, void* d_ws, size_t ws_size,
                              hipStream_t stream) {
  (void)in_sizes; (void)n_in; (void)out_size; (void)ws_size;
  const float* slots = (const float*)d_in[0];
  const float* inputs = (const float*)d_in[1];
  const float* Wq  = (const float*)d_in[2];
  const float* Wk  = (const float*)d_in[3];
  const float* Wv  = (const float*)d_in[4];
  const float* wih = (const float*)d_in[5];
  const float* whh = (const float*)d_in[6];
  const float* bih = (const float*)d_in[7];
  const float* bhh = (const float*)d_in[8];
  const float* w1  = (const float*)d_in[9];
  const float* b1  = (const float*)d_in[10];
  const float* w2  = (const float*)d_in[11];
  const float* b2  = (const float*)d_in[12];
  const float* lnig = (const float*)d_in[13];
  const float* lnib = (const float*)d_in[14];
  const float* lnsg = (const float*)d_in[15];
  const float* lnsb = (const float*)d_in[16];
  const float* lnfg = (const float*)d_in[17];
  const float* lnfb = (const float*)d_in[18];

  char* ws = (char*)d_ws;
  unsigned short* kmat = (unsigned short*)(ws);
  unsigned short* vT   = (unsigned short*)(ws + 134217728L);
  unsigned short* qbuf = (unsigned short*)(ws + 268435456L);
  unsigned short* wkvT = (unsigned short*)(ws + 268566528L);
  float* nump = (float*)(ws + 268632064L);
  float* denp = (float*)(ws + 272826368L);
  float* sbuf = (float*)(ws + 272859136L);

  k0_prep<<<128, 256, 0, stream>>>(Wk, Wv, wkvT);
  k1_lnkv<<<8192, 256, 0, stream>>>(inputs, lnig, lnib, wkvT, kmat, vT);
  kq_init<<<32, 512, 0, stream>>>(slots, lnsg, lnsb, Wq, qbuf);
  for (int it = 0; it < 3; ++it) {
    k2_attn<<<dim3(16, 32), 256, 0, stream>>>(kmat, vT, qbuf, nump, denp);
    const float* sprev = (it == 0) ? slots : sbuf;
    float* sdst = (it == 2) ? (float*)d_out : sbuf;
    k3_update<<<32, 512, 0, stream>>>(sprev, nump, denp, wih, whh, bih, bhh,
                                      w1, b1, w2, b2, lnfg, lnfb, lnsg, lnsb, Wq,
                                      sdst, qbuf, (it < 2) ? 1 : 0);
  }
}